// Round 1
// baseline (277.249 us; speedup 1.0000x reference)
//
#include <hip/hip_runtime.h>
#include <stdint.h>

typedef __attribute__((ext_vector_type(8))) short short8;
typedef __attribute__((ext_vector_type(4))) float floatx4;
typedef __attribute__((ext_vector_type(4))) unsigned int uintx4;

static constexpr float kLog2e = 1.4426950408889634f;

__device__ __forceinline__ unsigned short f2bf_rne(float f) {
  uint32_t u = __float_as_uint(f);
  u += 0x7FFFu + ((u >> 16) & 1u);
  return (unsigned short)(u >> 16);
}

// Prep: etg[n][k] = bf16_rne(emb[k][n])  (B-operand, transposed for contiguous-k
// fragment loads), wbg[k] = (w[k]*log2e, b[k]*log2e) so exp(logit) == exp2(fma).
__global__ __launch_bounds__(256) void soft_emb_prep(
    const float* __restrict__ emb,          // [512][64]
    const float* __restrict__ pw,           // [512]
    const float* __restrict__ pb,           // [512]
    unsigned short* __restrict__ etg,       // [64][512] bf16
    float2* __restrict__ wbg) {             // [512]
  const int t = threadIdx.x;
  const int bk = blockIdx.x;                // 0..7, k-range [bk*64, bk*64+64)
  const int n = t & 63;
  const int k0 = bk * 64 + (t >> 6) * 16;
  #pragma unroll
  for (int i = 0; i < 16; ++i) {
    float v = emb[(size_t)(k0 + i) * 64 + n];   // coalesced across lanes (n fast)
    etg[n * 512 + k0 + i] = f2bf_rne(v);
  }
  if (bk == 0) {
    #pragma unroll
    for (int j = 0; j < 2; ++j) {
      int k = t + j * 256;
      wbg[k] = make_float2(pw[k] * kLog2e, pb[k] * kLog2e);
    }
  }
}

// Main: fused logits -> exp -> (unnormalized) weights @ emb via bf16 MFMA,
// denominator via a 5th MFMA against a ones-column B fragment, rcp post-scale.
// Block = 256 thr = 4 waves; wave handles 2 rounds x 4 M-blocks x 16 tokens = 128.
// Grid 1600 -> 819200 tokens exactly.
__global__ __launch_bounds__(256, 2) void soft_emb_main(
    const float* __restrict__ x,            // [819200]
    const unsigned short* __restrict__ etg, // [64][512] bf16
    const float2* __restrict__ wbg,         // [512]
    float* __restrict__ out) {              // [819200][64]
  __shared__ __align__(16) unsigned short ET[64 * 512];  // 64 KB exactly -> 2 blocks/CU

  const int tid = threadIdx.x;
  {  // stage ET: 4096 x 16B chunks, coalesced dwordx4
    const uintx4* g = (const uintx4*)etg;
    uintx4* l = (uintx4*)ET;
    #pragma unroll
    for (int i = 0; i < 16; ++i) l[i * 256 + tid] = g[i * 256 + tid];
  }
  __syncthreads();

  const int lane = tid & 63;
  const int wv = tid >> 6;
  const int n15 = lane & 15;   // MFMA m/n index
  const int q = lane >> 4;     // MFMA k-quad

  union U8 { uint32_t u[4]; short8 s; };
  U8 ones;  // B fragment: column 0 = 1.0, rest 0 -> D[:,0] = row sums (denominator)
  {
    uint32_t ov = (n15 == 0) ? 0x3F803F80u : 0u;
    ones.u[0] = ones.u[1] = ones.u[2] = ones.u[3] = ov;
  }

  const int base0 = blockIdx.x * 512 + wv * 128;

  #pragma unroll 1
  for (int round = 0; round < 2; ++round) {
    const int tok0 = base0 + round * 64;
    float xv[4];
    #pragma unroll
    for (int t = 0; t < 4; ++t) xv[t] = x[tok0 + t * 16 + n15];  // m = n15

    floatx4 acc[4][4];   // [mblock][ntile]
    floatx4 accD[4];     // denominator tiles
    #pragma unroll
    for (int t = 0; t < 4; ++t) {
      accD[t] = floatx4{0.f, 0.f, 0.f, 0.f};
      #pragma unroll
      for (int ti = 0; ti < 4; ++ti) acc[t][ti] = floatx4{0.f, 0.f, 0.f, 0.f};
    }

    #pragma unroll 2
    for (int ks = 0; ks < 16; ++ks) {
      const int kk = ks * 32 + q * 8;   // this lane's 8 k's (A-frag layout)

      // w',b' pairs for k..k+7: 64B from global, L1-resident (4 KB table)
      float4 wbv[4];
      const float4* wp = (const float4*)(wbg + kk);
      #pragma unroll
      for (int jp = 0; jp < 4; ++jp) wbv[jp] = wp[jp];

      // B fragments: ET[n15+16*ti][kk..kk+7], ds_read_b128, 16-lane broadcast
      short8 bs[4];
      #pragma unroll
      for (int ti = 0; ti < 4; ++ti)
        bs[ti] = *(const short8*)(ET + ((n15 + 16 * ti) << 9) + kk);

      #pragma unroll
      for (int t = 0; t < 4; ++t) {
        U8 A;
        #pragma unroll
        for (int jp = 0; jp < 4; ++jp) {
          float e0 = __builtin_amdgcn_exp2f(fmaf(xv[t], wbv[jp].x, wbv[jp].y));
          float e1 = __builtin_amdgcn_exp2f(fmaf(xv[t], wbv[jp].z, wbv[jp].w));
          // pack hi16(e0),hi16(e1) with round-half-up: one perm per pair
          A.u[jp] = __builtin_amdgcn_perm(__float_as_uint(e1) + 0x8000u,
                                          __float_as_uint(e0) + 0x8000u,
                                          0x07060302u);
        }
        #pragma unroll
        for (int ti = 0; ti < 4; ++ti)
          acc[t][ti] = __builtin_amdgcn_mfma_f32_16x16x32_bf16(
              A.s, bs[ti], acc[t][ti], 0, 0, 0);
        accD[t] = __builtin_amdgcn_mfma_f32_16x16x32_bf16(
            A.s, ones.s, accD[t], 0, 0, 0);
      }
    }

    // Epilogue: C/D layout row=(q*4+reg), col=n15. Denominator for row q*4+r
    // lives in reg r of lane (q*16) -> one shuffle per reg.
    #pragma unroll
    for (int t = 0; t < 4; ++t) {
      #pragma unroll
      for (int r = 0; r < 4; ++r) {
        float den = __shfl(accD[t][r], lane & 48, 64);
        float inv = __builtin_amdgcn_rcpf(den);
        float* op = out + (size_t)(tok0 + t * 16 + q * 4 + r) * 64 + n15;
        op[0]  = acc[t][0][r] * inv;
        op[16] = acc[t][1][r] * inv;
        op[32] = acc[t][2][r] * inv;
        op[48] = acc[t][3][r] * inv;
      }
    }
  }
}

extern "C" void kernel_launch(void* const* d_in, const int* in_sizes, int n_in,
                              void* d_out, int out_size, void* d_ws, size_t ws_size,
                              hipStream_t stream) {
  (void)in_sizes; (void)n_in; (void)out_size; (void)ws_size;
  const float* x   = (const float*)d_in[0];   // [4096*200]
  const float* pw  = (const float*)d_in[1];   // [512]
  const float* pb  = (const float*)d_in[2];   // [512]
  const float* emb = (const float*)d_in[3];   // [512*64]
  unsigned short* etg = (unsigned short*)d_ws;            // 65536 B
  float2* wbg = (float2*)((char*)d_ws + 64 * 512 * 2);    // 4096 B
  float* out = (float*)d_out;

  soft_emb_prep<<<8, 256, 0, stream>>>(emb, pw, pb, etg, wbg);
  soft_emb_main<<<1600, 256, 0, stream>>>(x, etg, wbg, out);
}

// Round 2
// 267.202 us; speedup vs baseline: 1.0376x; 1.0376x over previous
//
#include <hip/hip_runtime.h>
#include <hip/hip_bf16.h>
#include <stdint.h>

typedef __attribute__((ext_vector_type(8))) short short8;
typedef __attribute__((ext_vector_type(4))) float floatx4;
typedef __attribute__((ext_vector_type(2))) float floatx2;
typedef __attribute__((ext_vector_type(4))) unsigned int uintx4;

static constexpr float kLog2e = 1.4426950408889634f;

__device__ __forceinline__ unsigned short f2bf_rne(float f) {
  uint32_t u = __float_as_uint(f);
  u += 0x7FFFu + ((u >> 16) & 1u);
  return (unsigned short)(u >> 16);
}

// Prep:
//  etg: emb^T in bf16, XOR-swizzled at 16B-chunk granularity:
//    element (n, k) stored at n*512 + (((k>>3) ^ (n&7))<<3) + (k&7)
//    -> main kernel's ds_read_b128 B-fragment reads hit all 32 banks evenly.
//  wbg4[p] = (w[2p], w[2p+1], b[2p], b[2p+1]) * log2e  -> one v_pk_fma_f32
//    per logit pair, exp(logit) == exp2(fma).
__global__ __launch_bounds__(256) void soft_emb_prep(
    const float* __restrict__ emb,          // [512][64]
    const float* __restrict__ pw,           // [512]
    const float* __restrict__ pb,           // [512]
    unsigned short* __restrict__ etg,       // [64][512] bf16, swizzled
    float4* __restrict__ wbg4) {            // [256]
  const int t = threadIdx.x;
  const int bk = blockIdx.x;                // 0..7
  const int n = t & 63;
  const int k0 = bk * 64 + (t >> 6) * 16;
  #pragma unroll
  for (int i = 0; i < 16; ++i) {
    const int k = k0 + i;
    float v = emb[(size_t)k * 64 + n];      // coalesced across lanes (n fast)
    etg[n * 512 + ((((k >> 3) ^ (n & 7)) << 3) | (k & 7))] = f2bf_rne(v);
  }
  if (bk == 0) {
    const int p = t;                        // 256 pairs
    wbg4[p] = make_float4(pw[2 * p] * kLog2e, pw[2 * p + 1] * kLog2e,
                          pb[2 * p] * kLog2e, pb[2 * p + 1] * kLog2e);
  }
}

// Main: fused logits -> exp2 -> bf16 MFMA weights@emb; denominator via a 5th
// MFMA against a ones-column B fragment; rcp post-scale.
// Block = 256 = 4 waves; wave owns 4 M-blocks x 16 tokens = 64 tokens.
// Grid 3200 x 256 tokens = 819200 exactly.
__global__ __launch_bounds__(256, 2) void soft_emb_main(
    const float* __restrict__ x,            // [819200]
    const unsigned short* __restrict__ etg, // [64][512] bf16, swizzled
    const float4* __restrict__ wbg4,        // [256]
    float* __restrict__ out) {              // [819200][64]
  __shared__ __align__(16) unsigned short ET[64 * 512];  // 64 KB -> 2 blocks/CU

  const int tid = threadIdx.x;
  {  // stage ET (already swizzled in global): straight 16B copy, coalesced
    const uintx4* g = (const uintx4*)etg;
    uintx4* l = (uintx4*)ET;
    #pragma unroll
    for (int i = 0; i < 16; ++i) l[i * 256 + tid] = g[i * 256 + tid];
  }
  __syncthreads();

  const int lane = tid & 63;
  const int wv = tid >> 6;
  const int n15 = lane & 15;   // MFMA m/n index
  const int q = lane >> 4;     // MFMA k-quad
  const int s = n15 & 7;       // swizzle key (row n -> n&7 == n15&7)

  union U8 { uint32_t u[4]; short8 v; };
  U8 ones;  // B fragment: column 0 = 1.0 -> D[:,0] = row sums (denominator)
  {
    uint32_t ov = (n15 == 0) ? 0x3F803F80u : 0u;
    ones.u[0] = ones.u[1] = ones.u[2] = ones.u[3] = ov;
  }

  const int tok0 = blockIdx.x * 256 + wv * 64;

  floatx2 xv2[4];
  #pragma unroll
  for (int t = 0; t < 4; ++t) {
    float xv = x[tok0 + t * 16 + n15];      // m = n15
    xv2[t] = floatx2{xv, xv};
  }

  int roff[4];
  #pragma unroll
  for (int ti = 0; ti < 4; ++ti) roff[ti] = (n15 + 16 * ti) << 9;

  floatx4 acc[4][4];   // [mblock][ntile]
  floatx4 accD[4];     // denominator tiles
  #pragma unroll
  for (int t = 0; t < 4; ++t) {
    accD[t] = floatx4{0.f, 0.f, 0.f, 0.f};
    #pragma unroll
    for (int ti = 0; ti < 4; ++ti) acc[t][ti] = floatx4{0.f, 0.f, 0.f, 0.f};
  }

  #pragma unroll 2
  for (int ks = 0; ks < 16; ++ks) {
    const int kk = ks * 32 + q * 8;         // this lane's 8 k's (A-frag layout)

    // (w0,w1,b0,b1) quads for k..k+7: 64B, L1-resident (4 KB table)
    float4 wbv[4];
    const float4* wp = wbg4 + (kk >> 1);
    #pragma unroll
    for (int jp = 0; jp < 4; ++jp) wbv[jp] = wp[jp];

    // B fragments: swizzled chunk (ks*4+q)^s, conflict-free ds_read_b128
    const int pc = ((((ks << 2) | q) ^ s) << 3);
    short8 bs[4];
    #pragma unroll
    for (int ti = 0; ti < 4; ++ti)
      bs[ti] = *(const short8*)(ET + roff[ti] + pc);

    #pragma unroll
    for (int t = 0; t < 4; ++t) {
      U8 A;
      #pragma unroll
      for (int jp = 0; jp < 4; ++jp) {
        // packed fma: (w0,w1) and (b0,b1) are adjacent regs -> v_pk_fma_f32
        floatx2 l2 = xv2[t] * floatx2{wbv[jp].x, wbv[jp].y}
                             + floatx2{wbv[jp].z, wbv[jp].w};
        float e0 = __builtin_amdgcn_exp2f(l2.x);
        float e1 = __builtin_amdgcn_exp2f(l2.y);
        union { __hip_bfloat162 h; uint32_t u32; } cv;
        cv.h = __float22bfloat162_rn(make_float2(e0, e1));  // low16 = e0
        A.u[jp] = cv.u32;
      }
      #pragma unroll
      for (int ti = 0; ti < 4; ++ti)
        acc[t][ti] = __builtin_amdgcn_mfma_f32_16x16x32_bf16(
            A.v, bs[ti], acc[t][ti], 0, 0, 0);
      accD[t] = __builtin_amdgcn_mfma_f32_16x16x32_bf16(
          A.v, ones.v, accD[t], 0, 0, 0);
    }
  }

  // Epilogue: C/D layout row=(q*4+reg), col=n15. Denominator for row q*4+r
  // lives in reg r of lane (q*16) -> one shuffle per reg.
  #pragma unroll
  for (int t = 0; t < 4; ++t) {
    #pragma unroll
    for (int r = 0; r < 4; ++r) {
      float den = __shfl(accD[t][r], lane & 48, 64);
      float inv = __builtin_amdgcn_rcpf(den);
      float* op = out + (size_t)(tok0 + t * 16 + q * 4 + r) * 64 + n15;
      op[0]  = acc[t][0][r] * inv;
      op[16] = acc[t][1][r] * inv;
      op[32] = acc[t][2][r] * inv;
      op[48] = acc[t][3][r] * inv;
    }
  }
}

extern "C" void kernel_launch(void* const* d_in, const int* in_sizes, int n_in,
                              void* d_out, int out_size, void* d_ws, size_t ws_size,
                              hipStream_t stream) {
  (void)in_sizes; (void)n_in; (void)out_size; (void)ws_size;
  const float* x   = (const float*)d_in[0];   // [4096*200]
  const float* pw  = (const float*)d_in[1];   // [512]
  const float* pb  = (const float*)d_in[2];   // [512]
  const float* emb = (const float*)d_in[3];   // [512*64]
  unsigned short* etg = (unsigned short*)d_ws;            // 65536 B
  float4* wbg4 = (float4*)((char*)d_ws + 64 * 512 * 2);   // 4096 B
  float* out = (float*)d_out;

  soft_emb_prep<<<8, 256, 0, stream>>>(emb, pw, pb, etg, wbg4);
  soft_emb_main<<<3200, 256, 0, stream>>>(x, etg, wbg4, out);
}